// Round 1
// baseline (203.291 us; speedup 1.0000x reference)
//
#include <hip/hip_runtime.h>

#define N_NODES 10000
#define N_EDGES 640000
#define D       128

// ---------------------------------------------------------------------------
// Kernel 1: Y = nodes @ W   (project FIRST; linearity lets us aggregate after)
// M-tile = 32 rows, full N=128, full K=128. 256 threads, each computes 2x8.
// ---------------------------------------------------------------------------
__global__ __launch_bounds__(256) void gemm_kernel(const float* __restrict__ nodes,
                                                   const float* __restrict__ Wm,
                                                   float* __restrict__ Y) {
    // stride 132 floats = 528 B: 16B-aligned rows AND row-pairs land on distinct banks
    __shared__ float As[32][132];
    const int t    = threadIdx.x;
    const int row0 = blockIdx.x * 32;

    // stage A tile: 32x128 floats = 1024 float4, 4 per thread
    for (int i = t; i < 1024; i += 256) {
        int r  = i >> 5;          // 32 float4 per row
        int c  = i & 31;
        int gr = row0 + r;
        float4 v = make_float4(0.f, 0.f, 0.f, 0.f);
        if (gr < N_NODES) v = ((const float4*)nodes)[gr * 32 + c];
        *((float4*)&As[r][c * 4]) = v;
    }
    __syncthreads();

    const int tx = t & 15;        // col group: cols tx*8 .. tx*8+7
    const int ty = t >> 4;        // row group: rows ty*2, ty*2+1
    const int c0 = tx * 8;
    const int r0 = ty * 2;

    float acc[2][8];
#pragma unroll
    for (int i = 0; i < 2; i++)
#pragma unroll
        for (int j = 0; j < 8; j++) acc[i][j] = 0.f;

    const float4* W4 = (const float4*)Wm;   // W rows are L2-resident (64 KB, all blocks share)
#pragma unroll 4
    for (int k = 0; k < 128; k++) {
        float  a0 = As[r0][k];
        float  a1 = As[r0 + 1][k];
        float4 w0 = W4[k * 32 + tx * 2];
        float4 w1 = W4[k * 32 + tx * 2 + 1];
        float  wv[8] = {w0.x, w0.y, w0.z, w0.w, w1.x, w1.y, w1.z, w1.w};
#pragma unroll
        for (int j = 0; j < 8; j++) {
            acc[0][j] += a0 * wv[j];
            acc[1][j] += a1 * wv[j];
        }
    }

#pragma unroll
    for (int i = 0; i < 2; i++) {
        int gr = row0 + r0 + i;
        if (gr < N_NODES) {
            float4 o0 = make_float4(acc[i][0], acc[i][1], acc[i][2], acc[i][3]);
            float4 o1 = make_float4(acc[i][4], acc[i][5], acc[i][6], acc[i][7]);
            ((float4*)Y)[gr * 32 + (c0 >> 2)]     = o0;
            ((float4*)Y)[gr * 32 + (c0 >> 2) + 1] = o1;
        }
    }
}

// ---------------------------------------------------------------------------
// Kernel 2: degree histogram (int atomics, 640k ops — cheap)
// ---------------------------------------------------------------------------
__global__ __launch_bounds__(256) void hist_kernel(const int* __restrict__ receivers,
                                                   int* __restrict__ deg) {
    int e = blockIdx.x * 256 + threadIdx.x;
    if (e < N_EDGES) atomicAdd(&deg[receivers[e]], 1);
}

// ---------------------------------------------------------------------------
// Kernel 3: single-block exclusive scan of degrees -> CSR offsets (+cursors)
// 1024 threads x 10 elems each covers 10240 >= 10000.
// ---------------------------------------------------------------------------
__global__ __launch_bounds__(1024) void scan_kernel(const int* __restrict__ deg,
                                                    int* __restrict__ off,
                                                    int* __restrict__ cur) {
    __shared__ int sums[1024];
    const int t    = threadIdx.x;
    const int CH   = 10;
    const int base = t * CH;

    int local[CH];
    int s = 0;
#pragma unroll
    for (int i = 0; i < CH; i++) {
        int idx = base + i;
        int v   = (idx < N_NODES) ? deg[idx] : 0;
        local[i] = s;
        s += v;
    }
    sums[t] = s;
    __syncthreads();

    // Hillis-Steele inclusive scan over the 1024 chunk sums
    for (int ofs = 1; ofs < 1024; ofs <<= 1) {
        int v = (t >= ofs) ? sums[t - ofs] : 0;
        __syncthreads();
        sums[t] += v;
        __syncthreads();
    }

    int prev = (t == 0) ? 0 : sums[t - 1];
#pragma unroll
    for (int i = 0; i < CH; i++) {
        int idx = base + i;
        if (idx < N_NODES) {
            int o = prev + local[i];
            off[idx] = o;
            cur[idx] = o;
        }
    }
    if (t == 1023) off[N_NODES] = prev + s;   // == N_EDGES
}

// ---------------------------------------------------------------------------
// Kernel 4: bucket-scatter edge senders into CSR slots
// ---------------------------------------------------------------------------
__global__ __launch_bounds__(256) void scatter_kernel(const int* __restrict__ senders,
                                                      const int* __restrict__ receivers,
                                                      int* __restrict__ cur,
                                                      int* __restrict__ csr) {
    int e = blockIdx.x * 256 + threadIdx.x;
    if (e < N_EDGES) {
        int r   = receivers[e];
        int pos = atomicAdd(&cur[r], 1);
        csr[pos] = senders[e];
    }
}

// ---------------------------------------------------------------------------
// Kernel 5: pull-gather. One 128-thread block per node.
// Thread layout: d4 = t&31 (float4 column), ep = t>>5 (4 edges in flight).
// Accumulate Y[sender] rows in registers, reduce the 4 edge-parallel partials
// through LDS, divide by degree, add bias.
// ---------------------------------------------------------------------------
__global__ __launch_bounds__(128) void gather_kernel(const float* __restrict__ Y,
                                                     const int* __restrict__ off,
                                                     const int* __restrict__ csr,
                                                     const float* __restrict__ bias,
                                                     float* __restrict__ out) {
    const int n  = blockIdx.x;
    const int t  = threadIdx.x;
    const int d4 = t & 31;
    const int ep = t >> 5;

    const int start = off[n];
    const int end   = off[n + 1];
    const int deg   = end - start;

    __shared__ int    lds_s[128];
    __shared__ float4 red[4][32];

    float4 acc = make_float4(0.f, 0.f, 0.f, 0.f);

    for (int c = start; c < end; c += 128) {
        int cnt = min(128, end - c);
        if (t < cnt) lds_s[t] = csr[c + t];
        __syncthreads();
        for (int j = ep; j < cnt; j += 4) {
            int    s = lds_s[j];
            float4 v = ((const float4*)Y)[s * 32 + d4];
            acc.x += v.x; acc.y += v.y; acc.z += v.z; acc.w += v.w;
        }
        __syncthreads();
    }

    red[ep][d4] = acc;
    __syncthreads();

    if (ep == 0) {
        float4 a0 = red[0][d4];
        float4 a1 = red[1][d4];
        float4 a2 = red[2][d4];
        float4 a3 = red[3][d4];
        float  inv = 1.0f / (float)max(deg, 1);
        float4 bv  = ((const float4*)bias)[d4];
        float4 o;
        o.x = (a0.x + a1.x + a2.x + a3.x) * inv + bv.x;
        o.y = (a0.y + a1.y + a2.y + a3.y) * inv + bv.y;
        o.z = (a0.z + a1.z + a2.z + a3.z) * inv + bv.z;
        o.w = (a0.w + a1.w + a2.w + a3.w) * inv + bv.w;
        ((float4*)out)[n * 32 + d4] = o;
    }
}

// ---------------------------------------------------------------------------
extern "C" void kernel_launch(void* const* d_in, const int* in_sizes, int n_in,
                              void* d_out, int out_size, void* d_ws, size_t ws_size,
                              hipStream_t stream) {
    const float* nodes     = (const float*)d_in[0];
    const int*   senders   = (const int*)  d_in[1];
    const int*   receivers = (const int*)  d_in[2];
    const float* Wm        = (const float*)d_in[3];
    const float* bias      = (const float*)d_in[4];
    float*       out       = (float*)d_out;

    // workspace layout (bytes), all 512B-aligned regions
    char*  w   = (char*)d_ws;
    float* Y   = (float*)(w);                 // 10000*128*4 = 5,120,000
    int*   deg = (int*)  (w + 5120000);       //     40,000
    int*   off = (int*)  (w + 5160448);       //     40,004
    int*   cur = (int*)  (w + 5201408);       //     40,000
    int*   csr = (int*)  (w + 5241856);       //  2,560,000  (end ~7.8 MB)

    // zero only what is read-before-write (deg); everything else fully written
    hipMemsetAsync(deg, 0, N_NODES * sizeof(int), stream);

    gemm_kernel<<<(N_NODES + 31) / 32, 256, 0, stream>>>(nodes, Wm, Y);
    hist_kernel<<<(N_EDGES + 255) / 256, 256, 0, stream>>>(receivers, deg);
    scan_kernel<<<1, 1024, 0, stream>>>(deg, off, cur);
    scatter_kernel<<<(N_EDGES + 255) / 256, 256, 0, stream>>>(senders, receivers, cur, csr);
    gather_kernel<<<N_NODES, 128, 0, stream>>>(Y, off, csr, bias, out);
}

// Round 2
// 160.147 us; speedup vs baseline: 1.2694x; 1.2694x over previous
//
#include <hip/hip_runtime.h>

#define N_NODES 10000
#define N_EDGES 640000
#define D       128

// pack two fp32 -> two bf16 (RNE) in one uint (low = a, high = b)
__device__ inline unsigned bf16pair(float a, float b) {
    unsigned ua = __float_as_uint(a), ub = __float_as_uint(b);
    ua = (ua + 0x7fffu + ((ua >> 16) & 1u)) >> 16;
    ub = (ub + 0x7fffu + ((ub >> 16) & 1u)) >> 16;
    return ua | (ub << 16);
}

// ---------------------------------------------------------------------------
// Kernel 1: Y = nodes @ W, stored as bf16 (halves the gather's read traffic).
// M-tile 32, 256 threads, each computes 2 rows x 8 cols.
// ---------------------------------------------------------------------------
__global__ __launch_bounds__(256) void gemm_kernel(const float* __restrict__ nodes,
                                                   const float* __restrict__ Wm,
                                                   unsigned* __restrict__ Yb) {
    __shared__ float As[32][132];
    const int t    = threadIdx.x;
    const int row0 = blockIdx.x * 32;

    for (int i = t; i < 1024; i += 256) {
        int r  = i >> 5;
        int c  = i & 31;
        int gr = row0 + r;
        float4 v = make_float4(0.f, 0.f, 0.f, 0.f);
        if (gr < N_NODES) v = ((const float4*)nodes)[gr * 32 + c];
        *((float4*)&As[r][c * 4]) = v;
    }
    __syncthreads();

    const int tx = t & 15;
    const int ty = t >> 4;
    const int c0 = tx * 8;
    const int r0 = ty * 2;

    float acc[2][8];
#pragma unroll
    for (int i = 0; i < 2; i++)
#pragma unroll
        for (int j = 0; j < 8; j++) acc[i][j] = 0.f;

    const float4* W4 = (const float4*)Wm;
#pragma unroll 4
    for (int k = 0; k < 128; k++) {
        float  a0 = As[r0][k];
        float  a1 = As[r0 + 1][k];
        float4 w0 = W4[k * 32 + tx * 2];
        float4 w1 = W4[k * 32 + tx * 2 + 1];
        float  wv[8] = {w0.x, w0.y, w0.z, w0.w, w1.x, w1.y, w1.z, w1.w};
#pragma unroll
        for (int j = 0; j < 8; j++) {
            acc[0][j] += a0 * wv[j];
            acc[1][j] += a1 * wv[j];
        }
    }

    // epilogue: pack 8 fp32 -> 4 uints (8 bf16) = one uint4 store per row
#pragma unroll
    for (int i = 0; i < 2; i++) {
        int gr = row0 + r0 + i;
        if (gr < N_NODES) {
            uint4 o;
            o.x = bf16pair(acc[i][0], acc[i][1]);
            o.y = bf16pair(acc[i][2], acc[i][3]);
            o.z = bf16pair(acc[i][4], acc[i][5]);
            o.w = bf16pair(acc[i][6], acc[i][7]);
            ((uint4*)Yb)[gr * 16 + (c0 >> 3)] = o;   // row = 128 bf16 = 16 uint4
        }
    }
}

// ---------------------------------------------------------------------------
// Kernel 2: degree histogram + rank capture. The atomicAdd's return value IS
// the edge's slot within its receiver bucket — saves the scatter's atomics.
// 4 edges/thread via int4.
// ---------------------------------------------------------------------------
__global__ __launch_bounds__(256) void hist_kernel(const int* __restrict__ receivers,
                                                   int* __restrict__ deg,
                                                   int* __restrict__ rank) {
    int i = blockIdx.x * 256 + threadIdx.x;   // group-of-4 index (640000/4 exact)
    int4 r = ((const int4*)receivers)[i];
    int4 k;
    k.x = atomicAdd(&deg[r.x], 1);
    k.y = atomicAdd(&deg[r.y], 1);
    k.z = atomicAdd(&deg[r.z], 1);
    k.w = atomicAdd(&deg[r.w], 1);
    ((int4*)rank)[i] = k;
}

// ---------------------------------------------------------------------------
// Kernel 3: exclusive scan of degrees -> CSR offsets. Wave-shuffle scan:
// 1024 thr x 10 elems; intra-wave __shfl_up scan, 16 wave sums scanned by
// wave 0. Two barriers total.
// ---------------------------------------------------------------------------
__global__ __launch_bounds__(1024) void scan_kernel(const int* __restrict__ deg,
                                                    int* __restrict__ off) {
    const int t    = threadIdx.x;
    const int CH   = 10;
    const int base = t * CH;

    int local[CH];
    int s = 0;
#pragma unroll
    for (int i = 0; i < CH; i++) {
        int idx = base + i;
        int v   = (idx < N_NODES) ? deg[idx] : 0;
        local[i] = s;
        s += v;
    }

    const int lane = t & 63;
    const int wv   = t >> 6;
    int x = s;                         // inclusive scan of chunk sums within wave
#pragma unroll
    for (int o = 1; o < 64; o <<= 1) {
        int y = __shfl_up(x, o);
        if (lane >= o) x += y;
    }

    __shared__ int wsum[16];
    if (lane == 63) wsum[wv] = x;
    __syncthreads();

    if (t < 16) {
        int y = wsum[t];
#pragma unroll
        for (int o = 1; o < 16; o <<= 1) {
            int z = __shfl_up(y, o);
            if (t >= o) y += z;
        }
        wsum[t] = y;                   // inclusive wave-sum prefix
    }
    __syncthreads();

    int wprefix = (wv == 0) ? 0 : wsum[wv - 1];
    int incl    = wprefix + x;         // inclusive through this chunk
    int excl    = incl - s;            // exclusive prefix of this chunk
#pragma unroll
    for (int i = 0; i < CH; i++) {
        int idx = base + i;
        if (idx < N_NODES) off[idx] = excl + local[i];
    }
    if (t == 1023) off[N_NODES] = incl;   // == N_EDGES
}

// ---------------------------------------------------------------------------
// Kernel 4: atomic-free scatter — pos = off[r] + rank[e]; pure stores,
// no response dependency. 4 edges/thread.
// ---------------------------------------------------------------------------
__global__ __launch_bounds__(256) void scatter_kernel(const int* __restrict__ senders,
                                                      const int* __restrict__ receivers,
                                                      const int* __restrict__ rank,
                                                      const int* __restrict__ off,
                                                      int* __restrict__ csr) {
    int i = blockIdx.x * 256 + threadIdx.x;
    int4 s4 = ((const int4*)senders)[i];
    int4 r4 = ((const int4*)receivers)[i];
    int4 k4 = ((const int4*)rank)[i];
    csr[off[r4.x] + k4.x] = s4.x;
    csr[off[r4.y] + k4.y] = s4.y;
    csr[off[r4.z] + k4.z] = s4.z;
    csr[off[r4.w] + k4.w] = s4.w;
}

// ---------------------------------------------------------------------------
// Kernel 5: pull-gather over bf16 Y. One 128-thread block per node.
// d4 = t&31 (8B = 4 bf16 per lane), ep = t>>5 (4 edges in flight).
// fp32 accumulation; mean + bias; fp32 out.
// ---------------------------------------------------------------------------
__global__ __launch_bounds__(128) void gather_kernel(const unsigned* __restrict__ Yb,
                                                     const int* __restrict__ off,
                                                     const int* __restrict__ csr,
                                                     const float* __restrict__ bias,
                                                     float* __restrict__ out) {
    const int n  = blockIdx.x;
    const int t  = threadIdx.x;
    const int d4 = t & 31;
    const int ep = t >> 5;

    const int start = off[n];
    const int end   = off[n + 1];
    const int deg   = end - start;

    __shared__ int    lds_s[128];
    __shared__ float4 red[4][32];

    float4 acc = make_float4(0.f, 0.f, 0.f, 0.f);

    for (int c = start; c < end; c += 128) {
        int cnt = min(128, end - c);
        if (t < cnt) lds_s[t] = csr[c + t];
        __syncthreads();
        for (int j = ep; j < cnt; j += 4) {
            int  s = lds_s[j];
            uint2 v = ((const uint2*)Yb)[s * 32 + d4];   // 4 bf16
            acc.x += __uint_as_float(v.x << 16);
            acc.y += __uint_as_float(v.x & 0xffff0000u);
            acc.z += __uint_as_float(v.y << 16);
            acc.w += __uint_as_float(v.y & 0xffff0000u);
        }
        __syncthreads();
    }

    red[ep][d4] = acc;
    __syncthreads();

    if (ep == 0) {
        float4 a0 = red[0][d4];
        float4 a1 = red[1][d4];
        float4 a2 = red[2][d4];
        float4 a3 = red[3][d4];
        float  inv = 1.0f / (float)max(deg, 1);
        float4 bv  = ((const float4*)bias)[d4];
        float4 o;
        o.x = (a0.x + a1.x + a2.x + a3.x) * inv + bv.x;
        o.y = (a0.y + a1.y + a2.y + a3.y) * inv + bv.y;
        o.z = (a0.z + a1.z + a2.z + a3.z) * inv + bv.z;
        o.w = (a0.w + a1.w + a2.w + a3.w) * inv + bv.w;
        ((float4*)out)[n * 32 + d4] = o;
    }
}

// ---------------------------------------------------------------------------
extern "C" void kernel_launch(void* const* d_in, const int* in_sizes, int n_in,
                              void* d_out, int out_size, void* d_ws, size_t ws_size,
                              hipStream_t stream) {
    const float* nodes     = (const float*)d_in[0];
    const int*   senders   = (const int*)  d_in[1];
    const int*   receivers = (const int*)  d_in[2];
    const float* Wm        = (const float*)d_in[3];
    const float* bias      = (const float*)d_in[4];
    float*       out       = (float*)d_out;

    // workspace layout (bytes)
    char*     w    = (char*)d_ws;
    unsigned* Yb   = (unsigned*)(w);              // bf16 Y: 10000*128*2 = 2,560,000
    int*      rank = (int*)(w + 2560000);         // 2,560,000
    int*      deg  = (int*)(w + 5120000);         //    40,000
    int*      off  = (int*)(w + 5160448);         //    40,004
    int*      csr  = (int*)(w + 5201408);         // 2,560,000  (end ~7.76 MB)

    hipMemsetAsync(deg, 0, N_NODES * sizeof(int), stream);

    gemm_kernel<<<(N_NODES + 31) / 32, 256, 0, stream>>>(nodes, Wm, Yb);
    hist_kernel<<<N_EDGES / 4 / 256, 256, 0, stream>>>(receivers, deg, rank);
    scan_kernel<<<1, 1024, 0, stream>>>(deg, off);
    scatter_kernel<<<N_EDGES / 4 / 256, 256, 0, stream>>>(senders, receivers, rank, off, csr);
    gather_kernel<<<N_NODES, 128, 0, stream>>>(Yb, off, csr, bias, out);
}

// Round 3
// 156.362 us; speedup vs baseline: 1.3001x; 1.0242x over previous
//
#include <hip/hip_runtime.h>

#define N_NODES 10000
#define N_EDGES 640000
#define D       128

#define GEMM_BLOCKS 313            // ceil(10000/32)
#define HIST_BLOCKS 625            // 640000/4/256 exact
#define GROUPS       8             // XCD count; nodes split into 8 ranges of 1250
#define NODES_PER_GROUP 1250
#define BPG          125           // scatter blocks per group; 125*256*4*5 = 640000/group

// pack two fp32 -> two bf16 (RNE) in one uint (low = a, high = b)
__device__ inline unsigned bf16pair(float a, float b) {
    unsigned ua = __float_as_uint(a), ub = __float_as_uint(b);
    ua = (ua + 0x7fffu + ((ua >> 16) & 1u)) >> 16;
    ub = (ub + 0x7fffu + ((ub >> 16) & 1u)) >> 16;
    return ua | (ub << 16);
}

// ---------------------------------------------------------------------------
// Kernel 1 (fused): blocks [0,313) -> Y = nodes @ W stored bf16;
//                   blocks [313,938) -> degree histogram + rank capture.
// Independent work; fusing saves a dispatch and overlaps VALU-bound gemm
// with atomic-latency-bound hist.
// ---------------------------------------------------------------------------
__global__ __launch_bounds__(256) void gemm_hist_kernel(const float* __restrict__ nodes,
                                                        const float* __restrict__ Wm,
                                                        unsigned* __restrict__ Yb,
                                                        const int* __restrict__ receivers,
                                                        int* __restrict__ deg,
                                                        int* __restrict__ rank) {
    __shared__ float As[32][132];
    const int t = threadIdx.x;

    if (blockIdx.x < GEMM_BLOCKS) {
        const int row0 = blockIdx.x * 32;

        for (int i = t; i < 1024; i += 256) {
            int r  = i >> 5;
            int c  = i & 31;
            int gr = row0 + r;
            float4 v = make_float4(0.f, 0.f, 0.f, 0.f);
            if (gr < N_NODES) v = ((const float4*)nodes)[gr * 32 + c];
            *((float4*)&As[r][c * 4]) = v;
        }
        __syncthreads();

        const int tx = t & 15;
        const int ty = t >> 4;
        const int c0 = tx * 8;
        const int r0 = ty * 2;

        float acc[2][8];
#pragma unroll
        for (int i = 0; i < 2; i++)
#pragma unroll
            for (int j = 0; j < 8; j++) acc[i][j] = 0.f;

        const float4* W4 = (const float4*)Wm;
#pragma unroll 4
        for (int k = 0; k < 128; k++) {
            float  a0 = As[r0][k];
            float  a1 = As[r0 + 1][k];
            float4 w0 = W4[k * 32 + tx * 2];
            float4 w1 = W4[k * 32 + tx * 2 + 1];
            float  wv[8] = {w0.x, w0.y, w0.z, w0.w, w1.x, w1.y, w1.z, w1.w};
#pragma unroll
            for (int j = 0; j < 8; j++) {
                acc[0][j] += a0 * wv[j];
                acc[1][j] += a1 * wv[j];
            }
        }

#pragma unroll
        for (int i = 0; i < 2; i++) {
            int gr = row0 + r0 + i;
            if (gr < N_NODES) {
                uint4 o;
                o.x = bf16pair(acc[i][0], acc[i][1]);
                o.y = bf16pair(acc[i][2], acc[i][3]);
                o.z = bf16pair(acc[i][4], acc[i][5]);
                o.w = bf16pair(acc[i][6], acc[i][7]);
                ((uint4*)Yb)[gr * 16 + (c0 >> 3)] = o;
            }
        }
    } else {
        // hist: 4 edges/thread via int4; atomicAdd return value IS the rank
        int i = (blockIdx.x - GEMM_BLOCKS) * 256 + t;   // int4 index, exact cover
        int4 r = ((const int4*)receivers)[i];
        int4 k;
        k.x = atomicAdd(&deg[r.x], 1);
        k.y = atomicAdd(&deg[r.y], 1);
        k.z = atomicAdd(&deg[r.z], 1);
        k.w = atomicAdd(&deg[r.w], 1);
        ((int4*)rank)[i] = k;
    }
}

// ---------------------------------------------------------------------------
// Kernel 2: exclusive scan of degrees -> CSR offsets (wave-shuffle scan).
// ---------------------------------------------------------------------------
__global__ __launch_bounds__(1024) void scan_kernel(const int* __restrict__ deg,
                                                    int* __restrict__ off) {
    const int t    = threadIdx.x;
    const int CH   = 10;
    const int base = t * CH;

    int local[CH];
    int s = 0;
#pragma unroll
    for (int i = 0; i < CH; i++) {
        int idx = base + i;
        int v   = (idx < N_NODES) ? deg[idx] : 0;
        local[i] = s;
        s += v;
    }

    const int lane = t & 63;
    const int wv   = t >> 6;
    int x = s;
#pragma unroll
    for (int o = 1; o < 64; o <<= 1) {
        int y = __shfl_up(x, o);
        if (lane >= o) x += y;
    }

    __shared__ int wsum[16];
    if (lane == 63) wsum[wv] = x;
    __syncthreads();

    if (t < 16) {
        int y = wsum[t];
#pragma unroll
        for (int o = 1; o < 16; o <<= 1) {
            int z = __shfl_up(y, o);
            if (t >= o) y += z;
        }
        wsum[t] = y;
    }
    __syncthreads();

    int wprefix = (wv == 0) ? 0 : wsum[wv - 1];
    int incl    = wprefix + x;
    int excl    = incl - s;
#pragma unroll
    for (int i = 0; i < CH; i++) {
        int idx = base + i;
        if (idx < N_NODES) off[idx] = excl + local[i];
    }
    if (t == 1023) off[N_NODES] = incl;
}

// ---------------------------------------------------------------------------
// Kernel 3: XCD-range-partitioned scatter. Group x = blockIdx&7 (round-robin
// block->XCD heuristic) reads ALL edges but stores only receivers in node
// range [x*1250,(x+1)*1250) -> each XCD writes a disjoint contiguous csr
// region -> no cross-XCD 64B-line churn. Positions off[r]+rank[e] are
// identical to the unpartitioned version (bit-identical output).
// ---------------------------------------------------------------------------
__global__ __launch_bounds__(256) void scatter_kernel(const int* __restrict__ senders,
                                                      const int* __restrict__ receivers,
                                                      const int* __restrict__ rank,
                                                      const int* __restrict__ off,
                                                      int* __restrict__ csr) {
    const int x  = blockIdx.x & 7;            // target XCD / node range
    const int bg = blockIdx.x >> 3;           // block within group
    const int lo = x * NODES_PER_GROUP;
    const int hi = lo + NODES_PER_GROUP;
    const int t  = threadIdx.x;

#pragma unroll
    for (int it = 0; it < 5; it++) {
        int i = it * (BPG * 256) + bg * 256 + t;     // int4 index
        int4 s4 = ((const int4*)senders)[i];
        int4 r4 = ((const int4*)receivers)[i];
        int4 k4 = ((const int4*)rank)[i];
        if (r4.x >= lo && r4.x < hi) csr[off[r4.x] + k4.x] = s4.x;
        if (r4.y >= lo && r4.y < hi) csr[off[r4.y] + k4.y] = s4.y;
        if (r4.z >= lo && r4.z < hi) csr[off[r4.z] + k4.z] = s4.z;
        if (r4.w >= lo && r4.w < hi) csr[off[r4.w] + k4.w] = s4.w;
    }
}

// ---------------------------------------------------------------------------
// Kernel 4: pull-gather over bf16 Y. One 128-thread block per node.
// ---------------------------------------------------------------------------
__global__ __launch_bounds__(128) void gather_kernel(const unsigned* __restrict__ Yb,
                                                     const int* __restrict__ off,
                                                     const int* __restrict__ csr,
                                                     const float* __restrict__ bias,
                                                     float* __restrict__ out) {
    const int n  = blockIdx.x;
    const int t  = threadIdx.x;
    const int d4 = t & 31;
    const int ep = t >> 5;

    const int start = off[n];
    const int end   = off[n + 1];
    const int deg   = end - start;

    __shared__ int    lds_s[128];
    __shared__ float4 red[4][32];

    float4 acc = make_float4(0.f, 0.f, 0.f, 0.f);

    for (int c = start; c < end; c += 128) {
        int cnt = min(128, end - c);
        if (t < cnt) lds_s[t] = csr[c + t];
        __syncthreads();
        for (int j = ep; j < cnt; j += 4) {
            int   s = lds_s[j];
            uint2 v = ((const uint2*)Yb)[s * 32 + d4];   // 4 bf16
            acc.x += __uint_as_float(v.x << 16);
            acc.y += __uint_as_float(v.x & 0xffff0000u);
            acc.z += __uint_as_float(v.y << 16);
            acc.w += __uint_as_float(v.y & 0xffff0000u);
        }
        __syncthreads();
    }

    red[ep][d4] = acc;
    __syncthreads();

    if (ep == 0) {
        float4 a0 = red[0][d4];
        float4 a1 = red[1][d4];
        float4 a2 = red[2][d4];
        float4 a3 = red[3][d4];
        float  inv = 1.0f / (float)max(deg, 1);
        float4 bv  = ((const float4*)bias)[d4];
        float4 o;
        o.x = (a0.x + a1.x + a2.x + a3.x) * inv + bv.x;
        o.y = (a0.y + a1.y + a2.y + a3.y) * inv + bv.y;
        o.z = (a0.z + a1.z + a2.z + a3.z) * inv + bv.z;
        o.w = (a0.w + a1.w + a2.w + a3.w) * inv + bv.w;
        ((float4*)out)[n * 32 + d4] = o;
    }
}

// ---------------------------------------------------------------------------
extern "C" void kernel_launch(void* const* d_in, const int* in_sizes, int n_in,
                              void* d_out, int out_size, void* d_ws, size_t ws_size,
                              hipStream_t stream) {
    const float* nodes     = (const float*)d_in[0];
    const int*   senders   = (const int*)  d_in[1];
    const int*   receivers = (const int*)  d_in[2];
    const float* Wm        = (const float*)d_in[3];
    const float* bias      = (const float*)d_in[4];
    float*       out       = (float*)d_out;

    // workspace layout (bytes)
    char*     w    = (char*)d_ws;
    unsigned* Yb   = (unsigned*)(w);              // bf16 Y: 2,560,000
    int*      rank = (int*)(w + 2560000);         // 2,560,000
    int*      deg  = (int*)(w + 5120000);         //    40,000
    int*      off  = (int*)(w + 5160448);         //    40,004
    int*      csr  = (int*)(w + 5201408);         // 2,560,000

    hipMemsetAsync(deg, 0, N_NODES * sizeof(int), stream);

    gemm_hist_kernel<<<GEMM_BLOCKS + HIST_BLOCKS, 256, 0, stream>>>(
        nodes, Wm, Yb, receivers, deg, rank);
    scan_kernel<<<1, 1024, 0, stream>>>(deg, off);
    scatter_kernel<<<GROUPS * BPG, 256, 0, stream>>>(senders, receivers, rank, off, csr);
    gather_kernel<<<N_NODES, 128, 0, stream>>>(Yb, off, csr, bias, out);
}

// Round 4
// 141.237 us; speedup vs baseline: 1.4394x; 1.1071x over previous
//
#include <hip/hip_runtime.h>

#define N_NODES 10000
#define N_EDGES 640000
#define D       128

#define HB       128               // localhist blocks
#define CHUNK    5000              // edges per localhist block (128*5000=640000)
#define GROUPS   8                 // XCD count for partitioned scatter
#define NODES_PER_GROUP 1250
#define BPG      125               // scatter blocks per group; 125*256*4*5 = 640000

// pack two fp32 -> two bf16 (RNE) in one uint (low = a, high = b)
__device__ inline unsigned bf16pair(float a, float b) {
    unsigned ua = __float_as_uint(a), ub = __float_as_uint(b);
    ua = (ua + 0x7fffu + ((ua >> 16) & 1u)) >> 16;
    ub = (ub + 0x7fffu + ((ub >> 16) & 1u)) >> 16;
    return ua | (ub << 16);
}

// ---------------------------------------------------------------------------
// Kernel 1: Y = nodes @ W, stored bf16. M-tile 32, 256 thr, 2x8 per thread.
// ---------------------------------------------------------------------------
__global__ __launch_bounds__(256) void gemm_kernel(const float* __restrict__ nodes,
                                                   const float* __restrict__ Wm,
                                                   unsigned* __restrict__ Yb) {
    __shared__ float As[32][132];
    const int t    = threadIdx.x;
    const int row0 = blockIdx.x * 32;

    for (int i = t; i < 1024; i += 256) {
        int r  = i >> 5;
        int c  = i & 31;
        int gr = row0 + r;
        float4 v = make_float4(0.f, 0.f, 0.f, 0.f);
        if (gr < N_NODES) v = ((const float4*)nodes)[gr * 32 + c];
        *((float4*)&As[r][c * 4]) = v;
    }
    __syncthreads();

    const int tx = t & 15;
    const int ty = t >> 4;
    const int c0 = tx * 8;
    const int r0 = ty * 2;

    float acc[2][8];
#pragma unroll
    for (int i = 0; i < 2; i++)
#pragma unroll
        for (int j = 0; j < 8; j++) acc[i][j] = 0.f;

    const float4* W4 = (const float4*)Wm;
#pragma unroll 4
    for (int k = 0; k < 128; k++) {
        float  a0 = As[r0][k];
        float  a1 = As[r0 + 1][k];
        float4 w0 = W4[k * 32 + tx * 2];
        float4 w1 = W4[k * 32 + tx * 2 + 1];
        float  wv[8] = {w0.x, w0.y, w0.z, w0.w, w1.x, w1.y, w1.z, w1.w};
#pragma unroll
        for (int j = 0; j < 8; j++) {
            acc[0][j] += a0 * wv[j];
            acc[1][j] += a1 * wv[j];
        }
    }

#pragma unroll
    for (int i = 0; i < 2; i++) {
        int gr = row0 + r0 + i;
        if (gr < N_NODES) {
            uint4 o;
            o.x = bf16pair(acc[i][0], acc[i][1]);
            o.y = bf16pair(acc[i][2], acc[i][3]);
            o.z = bf16pair(acc[i][4], acc[i][5]);
            o.w = bf16pair(acc[i][6], acc[i][7]);
            ((uint4*)Yb)[gr * 16 + (c0 >> 3)] = o;
        }
    }
}

// ---------------------------------------------------------------------------
// Kernel 2: LDS local histogram — ZERO global atomics.
// Block b: cnt[10000] in LDS; lrank[e] = LDS atomicAdd(&cnt[r],1) for its
// 5000-edge chunk; then dump cnt -> bcnt[b][*] (coalesced).
// ---------------------------------------------------------------------------
__global__ __launch_bounds__(256) void localhist_kernel(const int* __restrict__ receivers,
                                                        int* __restrict__ lrank,
                                                        int* __restrict__ bcnt) {
    __shared__ int cnt[N_NODES];
    const int t = threadIdx.x;
    const int b = blockIdx.x;

    for (int n = t; n < N_NODES; n += 256) cnt[n] = 0;
    __syncthreads();

    const int base = b * CHUNK;
    for (int i = t; i < CHUNK; i += 256) {
        int e = base + i;
        int r = receivers[e];
        lrank[e] = atomicAdd(&cnt[r], 1);    // LDS atomic: ns-latency
    }
    __syncthreads();

    int* dst = bcnt + b * N_NODES;
    for (int n = t; n < N_NODES; n += 256) dst[n] = cnt[n];
}

// ---------------------------------------------------------------------------
// Kernel 3: column scan — convert bcnt[b][n] in place to exclusive prefix
// over b, and emit deg[n]. Thread per node; fully coalesced.
// ---------------------------------------------------------------------------
__global__ __launch_bounds__(256) void colscan_kernel(int* __restrict__ bcnt,
                                                      int* __restrict__ deg) {
    int n = blockIdx.x * 256 + threadIdx.x;
    if (n >= N_NODES) return;
    int run = 0;
    for (int b = 0; b < HB; b++) {
        int v = bcnt[b * N_NODES + n];
        bcnt[b * N_NODES + n] = run;
        run += v;
    }
    deg[n] = run;
}

// ---------------------------------------------------------------------------
// Kernel 4: exclusive scan of degrees -> CSR offsets (wave-shuffle scan).
// ---------------------------------------------------------------------------
__global__ __launch_bounds__(1024) void scan_kernel(const int* __restrict__ deg,
                                                    int* __restrict__ off) {
    const int t    = threadIdx.x;
    const int CH   = 10;
    const int base = t * CH;

    int local[CH];
    int s = 0;
#pragma unroll
    for (int i = 0; i < CH; i++) {
        int idx = base + i;
        int v   = (idx < N_NODES) ? deg[idx] : 0;
        local[i] = s;
        s += v;
    }

    const int lane = t & 63;
    const int wv   = t >> 6;
    int x = s;
#pragma unroll
    for (int o = 1; o < 64; o <<= 1) {
        int y = __shfl_up(x, o);
        if (lane >= o) x += y;
    }

    __shared__ int wsum[16];
    if (lane == 63) wsum[wv] = x;
    __syncthreads();

    if (t < 16) {
        int y = wsum[t];
#pragma unroll
        for (int o = 1; o < 16; o <<= 1) {
            int z = __shfl_up(y, o);
            if (t >= o) y += z;
        }
        wsum[t] = y;
    }
    __syncthreads();

    int wprefix = (wv == 0) ? 0 : wsum[wv - 1];
    int incl    = wprefix + x;
    int excl    = incl - s;
#pragma unroll
    for (int i = 0; i < CH; i++) {
        int idx = base + i;
        if (idx < N_NODES) off[idx] = excl + local[i];
    }
    if (t == 1023) off[N_NODES] = incl;
}

// ---------------------------------------------------------------------------
// Kernel 5: XCD-range-partitioned scatter, fully atomic-free.
// pos = off[r] + bcnt[b(e)][r] + lrank[e]. Group x stores only receivers in
// [x*1250,(x+1)*1250) -> disjoint csr regions per XCD, no line churn.
// CHUNK=5000 is a multiple of 4, so int4 groups never straddle chunks:
// b(e) = i4 / 1250.
// ---------------------------------------------------------------------------
__global__ __launch_bounds__(256) void scatter_kernel(const int* __restrict__ senders,
                                                      const int* __restrict__ receivers,
                                                      const int* __restrict__ lrank,
                                                      const int* __restrict__ bcnt,
                                                      const int* __restrict__ off,
                                                      int* __restrict__ csr) {
    const int x  = blockIdx.x & 7;
    const int bg = blockIdx.x >> 3;
    const int lo = x * NODES_PER_GROUP;
    const int hi = lo + NODES_PER_GROUP;
    const int t  = threadIdx.x;

#pragma unroll
    for (int it = 0; it < 5; it++) {
        int i = it * (BPG * 256) + bg * 256 + t;     // int4 index
        int  b  = i / (CHUNK / 4);                    // source localhist block
        const int* pre = bcnt + b * N_NODES;
        int4 s4 = ((const int4*)senders)[i];
        int4 r4 = ((const int4*)receivers)[i];
        int4 k4 = ((const int4*)lrank)[i];
        if (r4.x >= lo && r4.x < hi) csr[off[r4.x] + pre[r4.x] + k4.x] = s4.x;
        if (r4.y >= lo && r4.y < hi) csr[off[r4.y] + pre[r4.y] + k4.y] = s4.y;
        if (r4.z >= lo && r4.z < hi) csr[off[r4.z] + pre[r4.z] + k4.z] = s4.z;
        if (r4.w >= lo && r4.w < hi) csr[off[r4.w] + pre[r4.w] + k4.w] = s4.w;
    }
}

// ---------------------------------------------------------------------------
// Kernel 6: pull-gather over bf16 Y. One 128-thread block per node.
// ---------------------------------------------------------------------------
__global__ __launch_bounds__(128) void gather_kernel(const unsigned* __restrict__ Yb,
                                                     const int* __restrict__ off,
                                                     const int* __restrict__ csr,
                                                     const float* __restrict__ bias,
                                                     float* __restrict__ out) {
    const int n  = blockIdx.x;
    const int t  = threadIdx.x;
    const int d4 = t & 31;
    const int ep = t >> 5;

    const int start = off[n];
    const int end   = off[n + 1];
    const int deg   = end - start;

    __shared__ int    lds_s[128];
    __shared__ float4 red[4][32];

    float4 acc = make_float4(0.f, 0.f, 0.f, 0.f);

    for (int c = start; c < end; c += 128) {
        int cnt = min(128, end - c);
        if (t < cnt) lds_s[t] = csr[c + t];
        __syncthreads();
        for (int j = ep; j < cnt; j += 4) {
            int   s = lds_s[j];
            uint2 v = ((const uint2*)Yb)[s * 32 + d4];   // 4 bf16
            acc.x += __uint_as_float(v.x << 16);
            acc.y += __uint_as_float(v.x & 0xffff0000u);
            acc.z += __uint_as_float(v.y << 16);
            acc.w += __uint_as_float(v.y & 0xffff0000u);
        }
        __syncthreads();
    }

    red[ep][d4] = acc;
    __syncthreads();

    if (ep == 0) {
        float4 a0 = red[0][d4];
        float4 a1 = red[1][d4];
        float4 a2 = red[2][d4];
        float4 a3 = red[3][d4];
        float  inv = 1.0f / (float)max(deg, 1);
        float4 bv  = ((const float4*)bias)[d4];
        float4 o;
        o.x = (a0.x + a1.x + a2.x + a3.x) * inv + bv.x;
        o.y = (a0.y + a1.y + a2.y + a3.y) * inv + bv.y;
        o.z = (a0.z + a1.z + a2.z + a3.z) * inv + bv.z;
        o.w = (a0.w + a1.w + a2.w + a3.w) * inv + bv.w;
        ((float4*)out)[n * 32 + d4] = o;
    }
}

// ---------------------------------------------------------------------------
extern "C" void kernel_launch(void* const* d_in, const int* in_sizes, int n_in,
                              void* d_out, int out_size, void* d_ws, size_t ws_size,
                              hipStream_t stream) {
    const float* nodes     = (const float*)d_in[0];
    const int*   senders   = (const int*)  d_in[1];
    const int*   receivers = (const int*)  d_in[2];
    const float* Wm        = (const float*)d_in[3];
    const float* bias      = (const float*)d_in[4];
    float*       out       = (float*)d_out;

    // workspace layout (bytes)
    char*     w     = (char*)d_ws;
    unsigned* Yb    = (unsigned*)(w);               // bf16 Y: 2,560,000
    int*      lrank = (int*)(w + 2560000);          // 2,560,000
    int*      csr   = (int*)(w + 5120000);          // 2,560,000
    int*      bcnt  = (int*)(w + 7680000);          // 128*10000*4 = 5,120,000
    int*      deg   = (int*)(w + 12800000);         //    40,000
    int*      off   = (int*)(w + 12840192);         //    40,004   (end ~12.9 MB)

    gemm_kernel     <<<(N_NODES + 31) / 32, 256, 0, stream>>>(nodes, Wm, Yb);
    localhist_kernel<<<HB, 256, 0, stream>>>(receivers, lrank, bcnt);
    colscan_kernel  <<<(N_NODES + 255) / 256, 256, 0, stream>>>(bcnt, deg);
    scan_kernel     <<<1, 1024, 0, stream>>>(deg, off);
    scatter_kernel  <<<GROUPS * BPG, 256, 0, stream>>>(senders, receivers, lrank,
                                                       bcnt, off, csr);
    gather_kernel   <<<N_NODES, 128, 0, stream>>>(Yb, off, csr, bias, out);
}